// Round 6
// baseline (120.690 us; speedup 1.0000x reference)
//
#include <hip/hip_runtime.h>
#include <cstddef>
#include <cstdint>

// TemporalConvTranspose2d as per-band GEMM on MFMA (R6: latency-optimized staging).
// x: (B, N_BI*D_IN, T) fp32, chan = s*D_IN + d_in
// W: (D_OUT, D_IN, K_B, K_T) fp32; b: (D_OUT,); out: (B, N_BO*D_OUT, T) fp32
// Band n = 2q+p: sources s_j = q + j + p - 1 with kb = 2j+p, j in {0,1}.
// Causal time: y[t] = sum_kt W[..,kt] * x[t-2+kt].
// GEMM: out[dout,t] = sum_k A[dout,k] B[k,t], k = (j*3+kt)*32 + d_in (K=192).
// MFMA 16x16x32 bf16, fp32 accum. A frags precomputed in d_ws (wprep).
// B frags: one ds_read_b128 from bf16 LDS [band][t][d_in], 16B-chunk XOR swizzle.
//
// R6 changes vs verified R5 (layouts byte-identical):
//  - 512-thread blocks (8 waves), TT=252, XT rows staged = 256 (exactly 2
//    quad-slots per thread; 8 global float4 loads hoisted -> 1 latency round).
//  - last 4 MFMA columns read 4 uninitialized pad rows; garbage is
//    column-local in B so those columns are simply not stored.
//  - staging write order rotated by quad-group so each ds_write instruction
//    spans both LDS bank halves (t parities mixed).

typedef __bf16 bf16x8 __attribute__((ext_vector_type(8)));
typedef __bf16 bf16x4 __attribute__((ext_vector_type(4)));
typedef float  f32x4  __attribute__((ext_vector_type(4)));

#define D_IN_ 32
#define D_OUT_ 32
#define N_BI_ 32
#define N_BO_ 64
#define K_B_ 4
#define K_T_ 3
#define T_ 1000
#define B_ 8

#define TT_ 252                  // output t per block
#define XROWS_ 260               // LDS rows per band (256 staged + 4 pad)
#define ROWB_ 64                 // bytes per LDS row (32 d_in * 2B)
#define WT_ELEMS (2 * 6 * 2 * 64 * 8)   // 12288 bf16 = 24576 B

__device__ __forceinline__ int swz(int t) { return (t & 3) ^ ((t >> 2) & 3); }

// Build A fragments: wt[((p*6+ks)*2+mt)*64 + lane] = 8 bf16, lane layout:
// dout = mt*16 + (l&15), d_in = (l>>4)*8 + r, (j,kt) = (ks/3, ks%3), kb = 2j+p.
__global__ __launch_bounds__(256)
void wprep(const float* __restrict__ W, __bf16* __restrict__ wt) {
    int idx = blockIdx.x * 256 + threadIdx.x;
    if (idx >= WT_ELEMS) return;
    int r = idx & 7, l = (idx >> 3) & 63, mt = (idx >> 9) & 1, rest = idx >> 10;
    int ks = rest % 6, p = rest / 6;
    int dout = mt * 16 + (l & 15), din = (l >> 4) * 8 + r;
    int j = ks / 3, kt = ks % 3, kb = 2 * j + p;
    wt[idx] = (__bf16)W[((dout * D_IN_ + din) * K_B_ + kb) * K_T_ + kt];
}

__global__ __launch_bounds__(512, 4)
void tct_mfma(const float* __restrict__ x, const __bf16* __restrict__ wt,
              const float* __restrict__ bias, float* __restrict__ out)
{
    __shared__ unsigned char xl[2 * XROWS_ * ROWB_];   // 33280 B

    const int tid = threadIdx.x;
    const int l   = tid & 63;
    const int w   = tid >> 6;          // wave id 0..7: 32-t sub-chunk
    const int n   = blockIdx.y;
    const int bb  = blockIdx.z;
    const int p   = n & 1, q = n >> 1;
    const int t0  = blockIdx.x * TT_;
    const int tstart = t0 - 4;

    // ---- A fragments (block-constant weights, L2-hot) ----
    bf16x8 afrag[6][2];
    {
        const bf16x8* wp = (const bf16x8*)wt;
        const int base = p * 12 * 64;
#pragma unroll
        for (int ks = 0; ks < 6; ++ks)
#pragma unroll
            for (int mt = 0; mt < 2; ++mt)
                afrag[ks][mt] = wp[base + (ks * 2 + mt) * 64 + l];
    }

    // ---- stage x -> LDS bf16 [band j][t][d_in], swizzled, transposed ----
    // 64 quad-rows (t in [t0-4, t0+251]) over 32 quad-groups: 2 slots/thread.
    {
        const int g  = tid >> 4;       // quad-group 0..31
        const int u  = tid & 15;       // si*8 + dg
        const int si = u >> 3;         // source band index j
        const int dg = u & 7;          // d_in group of 4
        const int s  = q + si + p - 1;
        const bool bandok = (s >= 0) && (s < N_BI_);
        const float* xb = x + ((size_t)(bb * N_BI_ + (bandok ? s : 0)) * D_IN_ + dg * 4) * T_;
        unsigned char* lbase = xl + si * (XROWS_ * ROWB_);
        const int c = dg >> 1, h = dg & 1;

        f32x4 vv[2][4];
        bool ok[2];
        int tgs[2];
#pragma unroll
        for (int it = 0; it < 2; ++it) {
            const int tq = g + it * 32;
            const int tg = tstart + tq * 4;
            tgs[it] = tg;
            ok[it] = bandok && (tg >= 0) && (tg < T_);
#pragma unroll
            for (int i = 0; i < 4; ++i) {
                if (ok[it]) vv[it][i] = *(const f32x4*)(xb + (size_t)i * T_ + tg);
                else        vv[it][i] = (f32x4){0.f, 0.f, 0.f, 0.f};
            }
        }
#pragma unroll
        for (int it = 0; it < 2; ++it) {
            const int tq = g + it * 32;
#pragma unroll
            for (int jj = 0; jj < 4; ++jj) {
                const int k = (jj + g) & 3;          // parity rotation
                const int t = tq * 4 + k;
                bf16x4 row;
                row[0] = (__bf16)vv[it][0][k];
                row[1] = (__bf16)vv[it][1][k];
                row[2] = (__bf16)vv[it][2][k];
                row[3] = (__bf16)vv[it][3][k];
                *(bf16x4*)(lbase + t * ROWB_ + ((c ^ swz(t)) << 4) + (h << 3)) = row;
            }
        }
    }
    __syncthreads();

    // ---- MFMA main loop: 2 Ntiles x 6 Ksteps x 2 Mtiles per wave ----
    f32x4 acc[2][2];
#pragma unroll
    for (int mt = 0; mt < 2; ++mt)
#pragma unroll
        for (int nt = 0; nt < 2; ++nt)
#pragma unroll
            for (int r = 0; r < 4; ++r) acc[mt][nt][r] = 0.f;

    const int tl  = l & 15;
    const int cch = l >> 4;
#pragma unroll
    for (int nt = 0; nt < 2; ++nt) {
#pragma unroll
        for (int ks = 0; ks < 6; ++ks) {
            const int j  = ks / 3, kt = ks % 3;
            const int lt = w * 32 + nt * 16 + tl + kt + 2;   // <= 259
            const bf16x8 bfrag = *(const bf16x8*)(xl + j * (XROWS_ * ROWB_) + lt * ROWB_
                                                  + ((cch ^ swz(lt)) << 4));
            acc[0][nt] = __builtin_amdgcn_mfma_f32_16x16x32_bf16(afrag[ks][0], bfrag, acc[0][nt], 0, 0, 0);
            acc[1][nt] = __builtin_amdgcn_mfma_f32_16x16x32_bf16(afrag[ks][1], bfrag, acc[1][nt], 0, 0, 0);
        }
    }

    // ---- epilogue: C/D layout col=l&15 (t), row=(l>>4)*4+reg (dout) ----
    const int rbase = (l >> 4) * 4;
    float bv[2][4];
#pragma unroll
    for (int mt = 0; mt < 2; ++mt)
#pragma unroll
        for (int r = 0; r < 4; ++r) bv[mt][r] = bias[mt * 16 + rbase + r];

#pragma unroll
    for (int mt = 0; mt < 2; ++mt)
#pragma unroll
        for (int nt = 0; nt < 2; ++nt) {
            const int lcol = w * 32 + nt * 16 + tl;
            const int tcol = t0 + lcol;
            if (lcol < TT_ && tcol < T_) {
                float* op = out + ((size_t)(bb * N_BO_ + n) * D_OUT_ + mt * 16 + rbase) * T_ + tcol;
#pragma unroll
                for (int r = 0; r < 4; ++r)
                    op[(size_t)r * T_] = acc[mt][nt][r] + bv[mt][r];
            }
        }
}

// fp32 fallback (verified R3 structure) if ws too small for wprep output.
__global__ __launch_bounds__(256)
void tct_fallback(const float* __restrict__ x, const float* __restrict__ W,
                  const float* __restrict__ bias, float* __restrict__ out)
{
    const int lane = threadIdx.x & 63;
    const int wav  = __builtin_amdgcn_readfirstlane(threadIdx.x >> 6);
    const int dog  = wav * 8;
    const int n    = blockIdx.y;
    const int bb   = blockIdx.z;
    const int p    = n & 1;

    int t0 = blockIdx.x * 256 + lane * 4;
    const bool act = (t0 < T_);
    if (!act) t0 = T_ - 4;

    float acc[8][4];
#pragma unroll
    for (int i = 0; i < 8; ++i)
#pragma unroll
        for (int u = 0; u < 4; ++u) acc[i][u] = 0.f;

#pragma unroll
    for (int j = 0; j < 2; ++j) {
        const int s = (n + 2 * j + p - 2) >> 1;
        if (s < 0 || s >= N_BI_) continue;
        const int kb = 2 * j + p;
        const float* xband = x + (size_t)(bb * N_BI_ + s) * D_IN_ * T_;
        for (int d_in = 0; d_in < D_IN_; ++d_in) {
            const float* xr = xband + d_in * T_;
            const float4 xc = *(const float4*)(xr + t0);
            float4 xp = make_float4(0.f, 0.f, 0.f, 0.f);
            if (t0 > 0) xp = *(const float4*)(xr + t0 - 4);
            const float xv[6] = {xp.z, xp.w, xc.x, xc.y, xc.z, xc.w};
#pragma unroll
            for (int kt = 0; kt < K_T_; ++kt) {
                float wv[8];
#pragma unroll
                for (int i = 0; i < 8; ++i) {
                    const int widx = __builtin_amdgcn_readfirstlane(
                        (((dog + i) * D_IN_ + d_in) * K_B_ + kb) * K_T_ + kt);
                    wv[i] = W[widx];
                }
#pragma unroll
                for (int i = 0; i < 8; ++i)
#pragma unroll
                    for (int u = 0; u < 4; ++u)
                        acc[i][u] = fmaf(wv[i], xv[u + kt], acc[i][u]);
            }
        }
    }
    if (act) {
        float bvv[8];
#pragma unroll
        for (int i = 0; i < 8; ++i) bvv[i] = bias[dog + i];
        float* op = out + ((size_t)(bb * N_BO_ + n) * D_OUT_ + dog) * T_ + t0;
#pragma unroll
        for (int i = 0; i < 8; ++i) {
            float4 v;
            v.x = acc[i][0] + bvv[i];
            v.y = acc[i][1] + bvv[i];
            v.z = acc[i][2] + bvv[i];
            v.w = acc[i][3] + bvv[i];
            *(float4*)(op + (size_t)i * T_) = v;
        }
    }
}

extern "C" void kernel_launch(void* const* d_in, const int* in_sizes, int n_in,
                              void* d_out, int out_size, void* d_ws, size_t ws_size,
                              hipStream_t stream) {
    const float* x    = (const float*)d_in[0];
    const float* W    = (const float*)d_in[1];
    const float* bias = (const float*)d_in[2];
    float* out = (float*)d_out;

    if (ws_size >= (size_t)WT_ELEMS * sizeof(__bf16)) {
        __bf16* wt = (__bf16*)d_ws;
        wprep<<<(WT_ELEMS + 255) / 256, 256, 0, stream>>>(W, wt);
        dim3 grid((T_ + TT_ - 1) / TT_, N_BO_, B_);   // 4 x 64 x 8
        tct_mfma<<<grid, dim3(512), 0, stream>>>(x, wt, bias, out);
    } else {
        dim3 grid((T_ + 255) / 256, N_BO_, B_);
        tct_fallback<<<grid, dim3(256), 0, stream>>>(x, W, bias, out);
    }
}